// Round 5
// baseline (91.168 us; speedup 1.0000x reference)
//
#include <hip/hip_runtime.h>
#include <math.h>

#define T_TOK 1024
#define H_DIM 1024
#define NEXP  16
#define I_DIM 512
#define ISH   1024
#define GU_GRID 640
#define DN_GRID 1280

typedef __bf16 bf16;
typedef __bf16 bf16x4 __attribute__((ext_vector_type(4)));
typedef __bf16 bf16x8 __attribute__((ext_vector_type(8)));
typedef float  f32x4  __attribute__((ext_vector_type(4)));

#define MFMA(a,b,c) __builtin_amdgcn_mfma_f32_16x16x32_bf16(a,b,c,0,0,0)

// ---------------- fused cast(x->bf16) + router: 4 tokens/block, 1 wave/token ----------------
__global__ __launch_bounds__(256) void k_cast_router(const float* __restrict__ x,
        const float* __restrict__ gw, const float* __restrict__ bias,
        bf16* __restrict__ xb, int* __restrict__ tok_e, float* __restrict__ tok_w)
{
    int t = blockIdx.x * 4 + (threadIdx.x >> 6);
    int lane = threadIdx.x & 63;
    const float* xrow = x + (size_t)t * H_DIM + lane * 16;
    bf16* xbrow = xb + (size_t)t * H_DIM + lane * 16;
    float acc[NEXP];
    #pragma unroll
    for (int e = 0; e < NEXP; ++e) acc[e] = 0.f;
    #pragma unroll
    for (int kc = 0; kc < 4; ++kc) {
        float4 xv = *(const float4*)(xrow + kc * 4);
        bf16x4 o = { (bf16)xv.x, (bf16)xv.y, (bf16)xv.z, (bf16)xv.w };
        *(bf16x4*)(xbrow + kc * 4) = o;
        const float* gp = gw + lane * 16 + kc * 4;
        #pragma unroll
        for (int e = 0; e < NEXP; ++e) {
            float4 wv = *(const float4*)(gp + e * H_DIM);
            acc[e] += xv.x * wv.x + xv.y * wv.y + xv.z * wv.z + xv.w * wv.w;
        }
    }
    #pragma unroll
    for (int e = 0; e < NEXP; ++e) {
        float v = acc[e];
        #pragma unroll
        for (int off = 1; off < 64; off <<= 1) v += __shfl_xor(v, off);
        acc[e] = v;
    }
    if (lane == 0) {
        float sc[NEXP], bi[NEXP];
        #pragma unroll
        for (int e = 0; e < NEXP; ++e) {
            sc[e] = 1.f / (1.f + expf(-acc[e]));
            bi[e] = sc[e] + bias[e];
        }
        int i1 = 0; float b1 = bi[0];
        for (int e = 1; e < NEXP; ++e) if (bi[e] > b1) { b1 = bi[e]; i1 = e; }
        int i2 = -1; float b2 = -1e30f;
        for (int e = 0; e < NEXP; ++e) { if (e == i1) continue; if (bi[e] > b2) { b2 = bi[e]; i2 = e; } }
        float w1 = sc[i1], w2 = sc[i2];
        float s = w1 + w2;
        w1 /= s; w2 /= s;
        tok_e[t * 2]     = i1;  tok_e[t * 2 + 1] = i2;
        tok_w[t * 2]     = w1;  tok_w[t * 2 + 1] = w2;
    }
}

// ---------------- build: histogram + scan + scatter + worklists (one block) ----------------
__global__ __launch_bounds__(256) void k_build(const int* __restrict__ tok_e,
        const float* __restrict__ tok_w, int* __restrict__ offs_g,
        int* __restrict__ row_token, float* __restrict__ row_w,
        int* __restrict__ wl_gu, int* __restrict__ n_gu,
        int* __restrict__ wl_dn, int* __restrict__ n_dn)
{
    __shared__ int cnt[NEXP], cur[NEXP], tcnt[NEXP], toff[NEXP + 1];
    int tid = threadIdx.x;
    if (tid < NEXP) cnt[tid] = 0;
    __syncthreads();
    for (int p = tid; p < 2 * T_TOK; p += 256) atomicAdd(&cnt[tok_e[p]], 1);
    __syncthreads();
    if (tid == 0) {
        int s = 0, ts = 0;
        for (int e = 0; e < NEXP; ++e) {
            offs_g[e] = s; cur[e] = s;
            int c = cnt[e];
            tcnt[e] = (c + 63) >> 6;
            toff[e] = ts;
            ts += tcnt[e];
            s += c;
        }
        offs_g[NEXP] = s; toff[NEXP] = ts;
        *n_gu = ts * 8 + 256;
        *n_dn = ts * 16 + 512;
    }
    __syncthreads();
    for (int p = tid; p < 2 * T_TOK; p += 256) {
        int e = tok_e[p];
        int pos = atomicAdd(&cur[e], 1);
        row_token[pos] = p >> 1;
        row_w[pos] = tok_w[p];
    }
    int ntr = toff[NEXP];
    int tot_gu = ntr * 8 + 256;
    for (int idx = tid; idx < tot_gu; idx += 256) {
        int entry;
        if (idx < ntr * 8) {
            int t8 = idx >> 3;
            int e = 0;
            while (!(t8 >= toff[e] && t8 < toff[e + 1])) ++e;
            int j = idx - 8 * toff[e];
            int nx = j / tcnt[e], mt = j % tcnt[e];
            entry = (e << 16) | (mt << 8) | nx;
        } else {
            int j = idx - ntr * 8;
            int nx = j >> 4, mt = j & 15;
            entry = (1 << 30) | (mt << 8) | nx;
        }
        wl_gu[idx] = entry;
    }
    int tot_dn = ntr * 16 + 512;
    for (int idx = tid; idx < tot_dn; idx += 256) {
        int entry;
        if (idx < ntr * 16) {
            int t16 = idx >> 4;
            int e = 0;
            while (!(t16 >= toff[e] && t16 < toff[e + 1])) ++e;
            int j = idx - 16 * toff[e];
            int nx = j / tcnt[e], mt = j % tcnt[e];
            entry = (e << 16) | (mt << 8) | nx;
        } else {
            int j = idx - ntr * 16;
            int nx = j >> 5, r = j & 31;
            int mt = r >> 1, kh = r & 1;
            entry = (1 << 30) | (kh << 24) | (mt << 8) | nx;
        }
        wl_dn[idx] = entry;
    }
}

// ---------------- fused gate_up + SwiGLU, depth-1 reg-prefetch pipeline ----------------
__global__ __launch_bounds__(256) void k_gu_all(
    const bf16* __restrict__ xb, const float* __restrict__ wgu, const float* __restrict__ sgu,
    bf16* __restrict__ act, bf16* __restrict__ act2,
    const int* __restrict__ offs, const int* __restrict__ row_token,
    const int* __restrict__ wl, const int* __restrict__ n_wl)
{
    int bid = blockIdx.x;
    int idx = (bid & 7) * (GU_GRID >> 3) + (bid >> 3);
    if (idx >= *n_wl) return;
    int entry = wl[idx];
    bool sh = entry & (1 << 30);
    int mt = (entry >> 8) & 255, nx = entry & 255;
    int m0, mcnt, gup, e = 0;
    const float* W;
    bf16* dst;
    if (sh) { m0 = mt * 64; mcnt = 64; W = sgu; gup = ISH; dst = act2; }
    else {
        e = (entry >> 16) & 31;
        m0 = offs[e] + mt * 64; mcnt = min(64, offs[e + 1] - m0);
        W = wgu + (size_t)e * (2 * (size_t)I_DIM * H_DIM); gup = I_DIM; dst = act;
    }
    int n0 = nx * 64;

    __shared__ bf16 As[64][72];
    __shared__ bf16 Bg[64][72];
    __shared__ bf16 Bu[64][72];
    __shared__ int  toks[64];

    int tid = threadIdx.x;
    if (!sh) {
        if (tid < 64) toks[tid] = row_token[m0 + min(tid, mcnt - 1)];
        __syncthreads();
    }

    const float* gbase = W + (size_t)n0 * H_DIM;
    const float* ubase = W + (size_t)(gup + n0) * H_DIM;

    int lane = tid & 63, w = tid >> 6, wm = w >> 1, wn = w & 1;
    int lr = lane & 15, lk8 = (lane >> 4) * 8;

    f32x4 aG[2][2], aU[2][2];
    #pragma unroll
    for (int i = 0; i < 2; ++i)
        #pragma unroll
        for (int j = 0; j < 2; ++j) { aG[i][j] = (f32x4){0,0,0,0}; aU[i][j] = (f32x4){0,0,0,0}; }

    int r0 = tid >> 3, c8 = (tid & 7) * 8;
    int r1 = r0 + 32;
    int arow0, arow1;
    if (sh) { arow0 = m0 + r0; arow1 = m0 + r1; }
    else    { arow0 = toks[r0]; arow1 = toks[r1]; }
    const bf16* a_src0 = xb + (size_t)arow0 * H_DIM + c8;
    const bf16* a_src1 = xb + (size_t)arow1 * H_DIM + c8;
    const float* pg0 = gbase + (size_t)r0 * H_DIM + c8;
    const float* pg1 = gbase + (size_t)r1 * H_DIM + c8;
    const float* pu0 = ubase + (size_t)r0 * H_DIM + c8;
    const float* pu1 = ubase + (size_t)r1 * H_DIM + c8;

    bf16x8 ca0, ca1, na0, na1;
    float4 cg0, cg1, cg2, cg3, cu0, cu1, cu2, cu3;
    float4 ng0, ng1, ng2, ng3, nu0, nu1, nu2, nu3;

#define GU_LOAD(A0,A1,G0,G1,G2,G3,U0,U1,U2,U3,K) \
    A0 = *(const bf16x8*)(a_src0 + (K)); \
    A1 = *(const bf16x8*)(a_src1 + (K)); \
    G0 = *(const float4*)(pg0 + (K));     G1 = *(const float4*)(pg0 + (K) + 4); \
    G2 = *(const float4*)(pg1 + (K));     G3 = *(const float4*)(pg1 + (K) + 4); \
    U0 = *(const float4*)(pu0 + (K));     U1 = *(const float4*)(pu0 + (K) + 4); \
    U2 = *(const float4*)(pu1 + (K));     U3 = *(const float4*)(pu1 + (K) + 4);

    GU_LOAD(ca0,ca1,cg0,cg1,cg2,cg3,cu0,cu1,cu2,cu3, 0)

    #pragma unroll 2
    for (int k0 = 0; k0 < H_DIM; k0 += 64) {
        *(bf16x8*)&As[r0][c8] = ca0;
        *(bf16x8*)&As[r1][c8] = ca1;
        {
            bf16x8 gA = { (bf16)cg0.x,(bf16)cg0.y,(bf16)cg0.z,(bf16)cg0.w,
                          (bf16)cg1.x,(bf16)cg1.y,(bf16)cg1.z,(bf16)cg1.w };
            bf16x8 gB = { (bf16)cg2.x,(bf16)cg2.y,(bf16)cg2.z,(bf16)cg2.w,
                          (bf16)cg3.x,(bf16)cg3.y,(bf16)cg3.z,(bf16)cg3.w };
            bf16x8 uA = { (bf16)cu0.x,(bf16)cu0.y,(bf16)cu0.z,(bf16)cu0.w,
                          (bf16)cu1.x,(bf16)cu1.y,(bf16)cu1.z,(bf16)cu1.w };
            bf16x8 uB = { (bf16)cu2.x,(bf16)cu2.y,(bf16)cu2.z,(bf16)cu2.w,
                          (bf16)cu3.x,(bf16)cu3.y,(bf16)cu3.z,(bf16)cu3.w };
            *(bf16x8*)&Bg[r0][c8] = gA;
            *(bf16x8*)&Bg[r1][c8] = gB;
            *(bf16x8*)&Bu[r0][c8] = uA;
            *(bf16x8*)&Bu[r1][c8] = uB;
        }
        __syncthreads();
        if (k0 + 64 < H_DIM) {
            GU_LOAD(na0,na1,ng0,ng1,ng2,ng3,nu0,nu1,nu2,nu3, k0 + 64)
        }
        #pragma unroll
        for (int ks = 0; ks < 2; ++ks) {
            bf16x8 fa0 = *(const bf16x8*)&As[wm * 32 + lr][ks * 32 + lk8];
            bf16x8 fa1 = *(const bf16x8*)&As[wm * 32 + 16 + lr][ks * 32 + lk8];
            bf16x8 fg0 = *(const bf16x8*)&Bg[wn * 32 + lr][ks * 32 + lk8];
            bf16x8 fg1 = *(const bf16x8*)&Bg[wn * 32 + 16 + lr][ks * 32 + lk8];
            bf16x8 fu0 = *(const bf16x8*)&Bu[wn * 32 + lr][ks * 32 + lk8];
            bf16x8 fu1 = *(const bf16x8*)&Bu[wn * 32 + 16 + lr][ks * 32 + lk8];
            aG[0][0] = MFMA(fa0, fg0, aG[0][0]);
            aG[0][1] = MFMA(fa0, fg1, aG[0][1]);
            aG[1][0] = MFMA(fa1, fg0, aG[1][0]);
            aG[1][1] = MFMA(fa1, fg1, aG[1][1]);
            aU[0][0] = MFMA(fa0, fu0, aU[0][0]);
            aU[0][1] = MFMA(fa0, fu1, aU[0][1]);
            aU[1][0] = MFMA(fa1, fu0, aU[1][0]);
            aU[1][1] = MFMA(fa1, fu1, aU[1][1]);
        }
        __syncthreads();
        ca0 = na0; ca1 = na1;
        cg0 = ng0; cg1 = ng1; cg2 = ng2; cg3 = ng3;
        cu0 = nu0; cu1 = nu1; cu2 = nu2; cu3 = nu3;
    }
#undef GU_LOAD

    #pragma unroll
    for (int mi = 0; mi < 2; ++mi) {
        #pragma unroll
        for (int j = 0; j < 4; ++j) {
            int rl = wm * 32 + mi * 16 + (lane >> 4) * 4 + j;
            if (rl < mcnt) {
                #pragma unroll
                for (int ni = 0; ni < 2; ++ni) {
                    float g = aG[mi][ni][j], u = aU[mi][ni][j];
                    float v = (g / (1.f + __expf(-g))) * u;
                    dst[(size_t)(m0 + rl) * gup + n0 + wn * 32 + ni * 16 + lr] = (bf16)v;
                }
            }
        }
    }
}

// ---------------- fused down (routed + shared K-split), depth-1 reg-prefetch pipeline ----------------
__global__ __launch_bounds__(256) void k_dn_all(
    const bf16* __restrict__ act, const bf16* __restrict__ act2,
    const float* __restrict__ wd, const float* __restrict__ sd, float* __restrict__ out,
    const int* __restrict__ offs, const int* __restrict__ row_token, const float* __restrict__ row_w,
    const int* __restrict__ wl, const int* __restrict__ n_wl)
{
    int bid = blockIdx.x;
    int idx = (bid & 7) * (DN_GRID >> 3) + (bid >> 3);
    if (idx >= *n_wl) return;
    int entry = wl[idx];
    bool sh = entry & (1 << 30);
    int mt = (entry >> 8) & 255, nx = entry & 255;
    int m0, mcnt, kb, lda, ldw, e = 0;
    const bf16* A;
    const float* W;
    if (sh) {
        int kh = (entry >> 24) & 1;
        m0 = mt * 64; mcnt = 64; A = act2; lda = ISH; W = sd; ldw = ISH; kb = kh * 512;
    } else {
        e = (entry >> 16) & 31;
        m0 = offs[e] + mt * 64; mcnt = min(64, offs[e + 1] - m0);
        A = act; lda = I_DIM; W = wd + (size_t)e * H_DIM * I_DIM; ldw = I_DIM; kb = 0;
    }
    int n0 = nx * 64;

    __shared__ bf16 As[64][72];
    __shared__ bf16 Bs[64][72];

    int tid = threadIdx.x;
    int lane = tid & 63, w = tid >> 6, wm = w >> 1, wn = w & 1;
    int lr = lane & 15, lk8 = (lane >> 4) * 8;

    f32x4 acc[2][2];
    #pragma unroll
    for (int i = 0; i < 2; ++i)
        #pragma unroll
        for (int j = 0; j < 2; ++j) acc[i][j] = (f32x4){0,0,0,0};

    int r0 = tid >> 3, c8 = (tid & 7) * 8;
    int r1 = r0 + 32;
    int arow0 = m0 + (sh ? r0 : min(r0, mcnt - 1));
    int arow1 = m0 + (sh ? r1 : min(r1, mcnt - 1));
    const bf16* a_src0 = A + (size_t)arow0 * lda + kb + c8;
    const bf16* a_src1 = A + (size_t)arow1 * lda + kb + c8;
    const float* wbase = W + (size_t)n0 * ldw + kb;
    const float* pb0 = wbase + (size_t)r0 * ldw + c8;
    const float* pb1 = wbase + (size_t)r1 * ldw + c8;

    bf16x8 ca0, ca1, na0, na1;
    float4 cb0, cb1, cb2, cb3, nb0, nb1, nb2, nb3;

#define DN_LOAD(A0,A1,B0,B1,B2,B3,K) \
    A0 = *(const bf16x8*)(a_src0 + (K)); \
    A1 = *(const bf16x8*)(a_src1 + (K)); \
    B0 = *(const float4*)(pb0 + (K));    B1 = *(const float4*)(pb0 + (K) + 4); \
    B2 = *(const float4*)(pb1 + (K));    B3 = *(const float4*)(pb1 + (K) + 4);

    DN_LOAD(ca0,ca1,cb0,cb1,cb2,cb3, 0)

    #pragma unroll 2
    for (int k0 = 0; k0 < 512; k0 += 64) {
        *(bf16x8*)&As[r0][c8] = ca0;
        *(bf16x8*)&As[r1][c8] = ca1;
        {
            bf16x8 bA = { (bf16)cb0.x,(bf16)cb0.y,(bf16)cb0.z,(bf16)cb0.w,
                          (bf16)cb1.x,(bf16)cb1.y,(bf16)cb1.z,(bf16)cb1.w };
            bf16x8 bB = { (bf16)cb2.x,(bf16)cb2.y,(bf16)cb2.z,(bf16)cb2.w,
                          (bf16)cb3.x,(bf16)cb3.y,(bf16)cb3.z,(bf16)cb3.w };
            *(bf16x8*)&Bs[r0][c8] = bA;
            *(bf16x8*)&Bs[r1][c8] = bB;
        }
        __syncthreads();
        if (k0 + 64 < 512) {
            DN_LOAD(na0,na1,nb0,nb1,nb2,nb3, k0 + 64)
        }
        #pragma unroll
        for (int ks = 0; ks < 2; ++ks) {
            bf16x8 fa0 = *(const bf16x8*)&As[wm * 32 + lr][ks * 32 + lk8];
            bf16x8 fa1 = *(const bf16x8*)&As[wm * 32 + 16 + lr][ks * 32 + lk8];
            bf16x8 fb0 = *(const bf16x8*)&Bs[wn * 32 + lr][ks * 32 + lk8];
            bf16x8 fb1 = *(const bf16x8*)&Bs[wn * 32 + 16 + lr][ks * 32 + lk8];
            acc[0][0] = MFMA(fa0, fb0, acc[0][0]);
            acc[0][1] = MFMA(fa0, fb1, acc[0][1]);
            acc[1][0] = MFMA(fa1, fb0, acc[1][0]);
            acc[1][1] = MFMA(fa1, fb1, acc[1][1]);
        }
        __syncthreads();
        ca0 = na0; ca1 = na1;
        cb0 = nb0; cb1 = nb1; cb2 = nb2; cb3 = nb3;
    }
#undef DN_LOAD

    #pragma unroll
    for (int mi = 0; mi < 2; ++mi) {
        #pragma unroll
        for (int j = 0; j < 4; ++j) {
            int rl = wm * 32 + mi * 16 + (lane >> 4) * 4 + j;
            if (rl < mcnt) {
                if (sh) {
                    #pragma unroll
                    for (int ni = 0; ni < 2; ++ni)
                        atomicAdd(&out[(size_t)(m0 + rl) * H_DIM + n0 + wn * 32 + ni * 16 + lr],
                                  acc[mi][ni][j]);
                } else {
                    int t = row_token[m0 + rl];
                    float wt = row_w[m0 + rl];
                    #pragma unroll
                    for (int ni = 0; ni < 2; ++ni)
                        atomicAdd(&out[(size_t)t * H_DIM + n0 + wn * 32 + ni * 16 + lr],
                                  wt * acc[mi][ni][j]);
                }
            }
        }
    }
}

extern "C" void kernel_launch(void* const* d_in, const int* in_sizes, int n_in,
                              void* d_out, int out_size, void* d_ws, size_t ws_size,
                              hipStream_t stream)
{
    (void)in_sizes; (void)n_in; (void)out_size; (void)ws_size;
    const float* x    = (const float*)d_in[0];
    const float* gw   = (const float*)d_in[1];
    const float* bias = (const float*)d_in[2];
    const float* wgu  = (const float*)d_in[3];
    const float* wd   = (const float*)d_in[4];
    const float* sgu  = (const float*)d_in[5];
    const float* sd   = (const float*)d_in[6];
    float* out = (float*)d_out;

    char* ws = (char*)d_ws;
    int*   offs_g    = (int*)(ws);
    int*   n_gu      = (int*)(ws + 128);
    int*   n_dn      = (int*)(ws + 132);
    int*   wl_gu     = (int*)(ws + 256);
    int*   wl_dn     = (int*)(ws + 4096);
    int*   tok_e     = (int*)(ws + 16384);
    float* tok_w     = (float*)(ws + 24576);
    int*   row_token = (int*)(ws + 32768);
    float* row_w     = (float*)(ws + 40960);
    bf16*  xb        = (bf16*)(ws + 65536);
    bf16*  act       = (bf16*)(ws + 65536 + (1 << 21));
    bf16*  act2      = (bf16*)(ws + 65536 + (2 << 21));

    hipMemsetAsync(out, 0, (size_t)T_TOK * H_DIM * sizeof(float), stream);
    k_cast_router<<<T_TOK / 4, 256, 0, stream>>>(x, gw, bias, xb, tok_e, tok_w);
    k_build<<<1, 256, 0, stream>>>(tok_e, tok_w, offs_g, row_token, row_w,
                                   wl_gu, n_gu, wl_dn, n_dn);
    k_gu_all<<<GU_GRID, 256, 0, stream>>>(xb, wgu, sgu, act, act2,
                                          offs_g, row_token, wl_gu, n_gu);
    k_dn_all<<<DN_GRID, 256, 0, stream>>>(act, act2, wd, sd, out,
                                          offs_g, row_token, row_w, wl_dn, n_dn);
}